// Round 1
// baseline (902.915 us; speedup 1.0000x reference)
//
#include <hip/hip_runtime.h>
#include <math.h>

// ---- problem dims ----
#define BB   16
#define SS   8
#define TKK  400
#define HH   256
#define EE   128
#define VV   50000
#define OOVV 50
#define HH2  512
#define STK  (SS*TKK)     // 3200
#define VOO  (VV+OOVV)    // 50050
#define NVBLK 196         // ceil(50000/256)

// ---- workspace offsets (floats) ----
#define OFF_X     0        // B*E      = 2048
#define OFF_ST    2048     // B*H2     = 8192   s_t_hat = [h,c]
#define OFF_SD    10240    // B*H2     = 8192   s_t_hat@Wd_sec+bd_sec
#define OFF_WD    18432    // B*H2     = 8192   s_t_hat@Wd_w+bd_w
#define OFF_BETA  26624    // B*S      = 128
#define OFF_SCSEC 26752    // B*S      = 128
#define OFF_SCW   26880    // B*S*TK   = 51200  (zero-init, atomic accum)
#define OFF_CT    78080    // B*H2     = 8192   (zero-init, atomic accum)
#define OFF_OUT1  86272    // B*H      = 4096
#define OFF_PGEN  90368    // B        = 16
#define OFF_PMAX  90384    // NVBLK*B  = 3136
#define OFF_PSUM  93520    // NVBLK*B  = 3136

// ---- output offsets (floats) ----
#define O_FD   0
#define O_H    800800
#define O_C    804896
#define O_CT   808992
#define O_ATTN 817184
#define O_PGEN 868384
#define O_COV  868400

__device__ __forceinline__ float sigm(float x){ return 1.0f/(1.0f+expf(-x)); }

__device__ __forceinline__ float wave_sum(float v){
  #pragma unroll
  for(int o=32;o>0;o>>=1) v += __shfl_xor(v,o);
  return v;
}
__device__ __forceinline__ float wave_max(float v){
  #pragma unroll
  for(int o=32;o>0;o>>=1) v = fmaxf(v,__shfl_xor(v,o));
  return v;
}

// zero SCW (51200) + CT (8192) = 59392 floats, contiguous. grid 232x256
__global__ void k_zero(float* ws){
  int i = blockIdx.x*256 + threadIdx.x;
  ws[OFF_SCW + i] = 0.0f;
}

// x = [c_t_1, emb[y]] @ W_xc + b_xc   grid 16 x 128
__global__ void k_x(const int* __restrict__ y, const float* __restrict__ ct1,
                    const float* __restrict__ emb, const float* __restrict__ Wxc,
                    const float* __restrict__ bxc, float* __restrict__ ws){
  int b = blockIdx.x, e = threadIdx.x;
  __shared__ float cat[HH2+EE];
  for(int k=e;k<HH2;k+=EE) cat[k] = ct1[b*HH2+k];
  int tok = y[b];
  cat[HH2+e] = emb[(size_t)tok*EE + e];
  __syncthreads();
  float acc = bxc[e];
  for(int k=0;k<HH2+EE;k++) acc += cat[k]*Wxc[k*EE+e];
  ws[OFF_X + b*EE + e] = acc;
}

// LSTM step -> h, c, s_t_hat.  grid 16 x 256
__global__ void k_lstm(const float* __restrict__ h0, const float* __restrict__ c0,
                       const float* __restrict__ Wih, const float* __restrict__ bih,
                       const float* __restrict__ Whh, const float* __restrict__ bhh,
                       float* __restrict__ ws, float* __restrict__ out){
  int b = blockIdx.x, j = threadIdx.x;
  __shared__ float xr[EE], hr[HH];
  if(j<EE) xr[j] = ws[OFF_X + b*EE + j];
  hr[j] = h0[b*HH+j];
  __syncthreads();
  float a0 = bih[j      ] + bhh[j      ];
  float a1 = bih[j+HH   ] + bhh[j+HH   ];
  float a2 = bih[j+2*HH ] + bhh[j+2*HH ];
  float a3 = bih[j+3*HH ] + bhh[j+3*HH ];
  for(int k=0;k<EE;k++){
    float a = xr[k]; const float* w = &Wih[k*4*HH + j];
    a0 += a*w[0]; a1 += a*w[HH]; a2 += a*w[2*HH]; a3 += a*w[3*HH];
  }
  for(int k=0;k<HH;k++){
    float a = hr[k]; const float* w = &Whh[k*4*HH + j];
    a0 += a*w[0]; a1 += a*w[HH]; a2 += a*w[2*HH]; a3 += a*w[3*HH];
  }
  float ig = sigm(a0), fg = sigm(a1), gg = tanhf(a2), og = sigm(a3);
  float c = fg*c0[b*HH+j] + ig*gg;
  float h = og*tanhf(c);
  out[O_H + b*HH + j] = h;
  out[O_C + b*HH + j] = c;
  ws[OFF_ST + b*HH2 + j]      = h;
  ws[OFF_ST + b*HH2 + HH + j] = c;
}

// sd = st@Wd_sec+bd_sec ; wd = st@Wd_w+bd_w.  grid (16,4) x 256
__global__ void k_proj(const float* __restrict__ Wdsec, const float* __restrict__ bdsec,
                       const float* __restrict__ Wdw,  const float* __restrict__ bdw,
                       float* __restrict__ ws){
  int b = blockIdx.x;
  int idx = blockIdx.y*256 + threadIdx.x;   // 0..1023
  __shared__ float st[HH2];
  st[threadIdx.x]     = ws[OFF_ST + b*HH2 + threadIdx.x];
  st[256+threadIdx.x] = ws[OFF_ST + b*HH2 + 256 + threadIdx.x];
  __syncthreads();
  const float* Wm; const float* bias; int n; float* dst;
  if(idx < HH2){ n = idx;       Wm = Wdsec; bias = bdsec; dst = &ws[OFF_SD + b*HH2 + n]; }
  else         { n = idx - HH2; Wm = Wdw;   bias = bdw;   dst = &ws[OFF_WD + b*HH2 + n]; }
  float acc = bias[n];
  for(int k=0;k<HH2;k++) acc += st[k]*Wm[k*HH2 + n];
  *dst = acc;
}

// section attention scores.  grid (16,8) x 256
__global__ void k_esec(const float* __restrict__ sec, const float* __restrict__ Whsec,
                       const float* __restrict__ vsec, float* __restrict__ ws){
  int b = blockIdx.x, s = blockIdx.y, tid = threadIdx.x;
  __shared__ float row[HH2];
  __shared__ float red[4];
  row[tid]     = sec[(b*SS+s)*HH2 + tid];
  row[256+tid] = sec[(b*SS+s)*HH2 + 256 + tid];
  __syncthreads();
  float part = 0.0f;
  #pragma unroll
  for(int rep=0;rep<2;rep++){
    int n = rep*256 + tid;
    float acc = ws[OFF_SD + b*HH2 + n];
    for(int k=0;k<HH2;k++) acc += row[k]*Whsec[k*HH2 + n];
    part += tanhf(acc)*vsec[n];
  }
  part = wave_sum(part);
  if((tid&63)==0) red[tid>>6] = part;
  __syncthreads();
  if(tid==0) ws[OFF_SCSEC + b*SS + s] = red[0]+red[1]+red[2]+red[3];
}

// beta = softmax(sc_sec)/sum.  1 block x 64
__global__ void k_beta(float* __restrict__ ws){
  int b = threadIdx.x;
  if(b < BB){
    float m = -1e30f;
    for(int s=0;s<SS;s++) m = fmaxf(m, ws[OFF_SCSEC+b*SS+s]);
    float e[SS]; float sum=0.0f;
    for(int s=0;s<SS;s++){ e[s] = expf(ws[OFF_SCSEC+b*SS+s]-m); sum += e[s]; }
    float sum2 = 0.0f;
    for(int s=0;s<SS;s++) sum2 += e[s]/sum;
    for(int s=0;s<SS;s++) ws[OFF_BETA+b*SS+s] = (e[s]/sum)/sum2;
  }
}

// big fused GEMM: sc_w[row] = sum_n tanh(enc[row,:]@Wh_w[:,n] + wd[b,n] + cov[row]*Wc_w[n]) * v_w[n]
// 64x64 tiles, 4x4 per thread, atomic partial row-sums over 8 col-blocks.
// grid (800, 8) x 256
__global__ __launch_bounds__(256) void k_gemm(
        const float* __restrict__ A, const float* __restrict__ Bw,
        const float* __restrict__ Wcw, const float* __restrict__ vw,
        const float* __restrict__ cover, float* __restrict__ ws){
  __shared__ float As[16][64];   // [k][row]
  __shared__ float Bs[16][64];   // [k][col]
  int tid = threadIdx.x;
  int tx = tid & 15, ty = tid >> 4;
  int row0 = blockIdx.x*64, col0 = blockIdx.y*64;
  int lr = tid >> 2;          // A-load row 0..63
  int lk = (tid & 3) * 4;     // A-load k offset
  int bk = tid >> 4;          // B-load k 0..15
  int bc = (tid & 15) * 4;    // B-load col
  float acc[4][4] = {};
  for(int k0=0;k0<HH2;k0+=16){
    float4 av = *(const float4*)&A[(size_t)(row0+lr)*HH2 + k0 + lk];
    float4 bv = *(const float4*)&Bw[(size_t)(k0+bk)*HH2 + col0 + bc];
    As[lk+0][lr]=av.x; As[lk+1][lr]=av.y; As[lk+2][lr]=av.z; As[lk+3][lr]=av.w;
    *(float4*)&Bs[bk][bc] = bv;
    __syncthreads();
    #pragma unroll
    for(int kk=0;kk<16;kk++){
      float4 a4 = *(const float4*)&As[kk][ty*4];
      float4 b4 = *(const float4*)&Bs[kk][tx*4];
      float ar[4] = {a4.x,a4.y,a4.z,a4.w};
      float br[4] = {b4.x,b4.y,b4.z,b4.w};
      #pragma unroll
      for(int i=0;i<4;i++)
        #pragma unroll
        for(int j=0;j<4;j++) acc[i][j] += ar[i]*br[j];
    }
    __syncthreads();
  }
  // epilogue: tile never crosses b (3200 % 64 == 0)
  int b = row0 / STK;
  float4 wd4 = *(const float4*)&ws[OFF_WD + b*HH2 + col0 + tx*4];
  float4 wc4 = *(const float4*)&Wcw[col0 + tx*4];
  float4 vw4 = *(const float4*)&vw[col0 + tx*4];
  #pragma unroll
  for(int i=0;i<4;i++){
    int rg = row0 + ty*4 + i;
    float cv = cover[rg];
    float rs = tanhf(acc[i][0] + wd4.x + cv*wc4.x)*vw4.x
             + tanhf(acc[i][1] + wd4.y + cv*wc4.y)*vw4.y
             + tanhf(acc[i][2] + wd4.z + cv*wc4.z)*vw4.z
             + tanhf(acc[i][3] + wd4.w + cv*wc4.w)*vw4.w;
    #pragma unroll
    for(int o=8;o>0;o>>=1) rs += __shfl_xor(rs,o,16);
    if(tx==0) atomicAdd(&ws[OFF_SCW + rg], rs);
  }
}

// attn softmax over 3200 with beta weighting + mask + renorm; also coverage out.
// grid 16 x 256
__global__ void k_attn(const float* __restrict__ mask, const float* __restrict__ cover,
                       float* __restrict__ ws, float* __restrict__ out){
  int b = blockIdx.x, tid = threadIdx.x;
  __shared__ float vals[STK];
  __shared__ float red[4];
  int lane = tid & 63, w = tid >> 6;
  float m = -1e30f;
  for(int j=tid;j<STK;j+=256){
    float v = ws[OFF_BETA + b*SS + j/TKK] * ws[OFF_SCW + b*STK + j];
    vals[j] = v; m = fmaxf(m, v);
  }
  m = wave_max(m);
  if(lane==0) red[w] = m;
  __syncthreads();
  m = fmaxf(fmaxf(red[0],red[1]), fmaxf(red[2],red[3]));
  __syncthreads();
  float ssum = 0.0f;
  for(int j=tid;j<STK;j+=256){
    float e = expf(vals[j]-m) * mask[b*STK + j];
    vals[j] = e; ssum += e;
  }
  ssum = wave_sum(ssum);
  if(lane==0) red[w] = ssum;
  __syncthreads();
  float inv = 1.0f/(red[0]+red[1]+red[2]+red[3]);
  for(int j=tid;j<STK;j+=256){
    float a = vals[j]*inv;
    out[O_ATTN + b*STK + j] = a;
    out[O_COV  + b*STK + j] = cover[b*STK + j] + a;
  }
}

// c_t = attn @ enc.  grid (25,16) x 256, atomic accumulate
__global__ void k_ct(const float* __restrict__ enc, const float* __restrict__ out,
                     float* __restrict__ ws){
  int b = blockIdx.y, tc = blockIdx.x, tid = threadIdx.x;
  __shared__ float a[128];
  int t0 = tc*128;
  if(tid<128) a[tid] = out[O_ATTN + b*STK + t0 + tid];
  __syncthreads();
  float acc0=0.0f, acc1=0.0f;
  for(int tt=0;tt<128;tt++){
    const float* row = &enc[(size_t)(b*STK + t0 + tt)*HH2];
    float av = a[tt];
    acc0 += av*row[tid];
    acc1 += av*row[256+tid];
  }
  atomicAdd(&ws[OFF_CT + b*HH2 + tid],       acc0);
  atomicAdd(&ws[OFF_CT + b*HH2 + 256 + tid], acc1);
}

// p_gen + out1 + copy c_t to output.  grid 16 x 256
__global__ void k_pgen(const float* __restrict__ Wp, const float* __restrict__ bp,
                       const float* __restrict__ Wo1, const float* __restrict__ bo1,
                       float* __restrict__ ws, float* __restrict__ out){
  int b = blockIdx.x, tid = threadIdx.x;
  __shared__ float cat[4*HH+EE];  // [c_t(512), st(512), x(128)]
  __shared__ float red[4];
  cat[tid]       = ws[OFF_CT + b*HH2 + tid];
  cat[256+tid]   = ws[OFF_CT + b*HH2 + 256 + tid];
  cat[512+tid]   = ws[OFF_ST + b*HH2 + tid];
  cat[768+tid]   = ws[OFF_ST + b*HH2 + 256 + tid];
  if(tid<EE) cat[1024+tid] = ws[OFF_X + b*EE + tid];
  __syncthreads();
  float p = 0.0f;
  for(int k=tid;k<4*HH+EE;k+=256) p += cat[k]*Wp[k];
  p = wave_sum(p);
  if((tid&63)==0) red[tid>>6] = p;
  __syncthreads();
  if(tid==0){
    float pg = sigm(red[0]+red[1]+red[2]+red[3] + bp[0]);
    ws[OFF_PGEN + b] = pg;
    out[O_PGEN + b]  = pg;
  }
  // out1[b,tid] = [h, c_t] @ W_out1 + b_out1 ; h = cat[512..768), c_t = cat[0..512)
  float acc = bo1[tid];
  for(int k=0;k<HH;k++)  acc += cat[512+k]*Wo1[k*HH + tid];
  for(int k=0;k<HH2;k++) acc += cat[k]*Wo1[(HH+k)*HH + tid];
  ws[OFF_OUT1 + b*HH + tid] = acc;
  out[O_CT + b*HH2 + tid]       = cat[tid];
  out[O_CT + b*HH2 + 256 + tid] = cat[256+tid];
}

// logits -> final_dist area (in place), per-block per-b max.  grid 196 x 256
__global__ void k_logits(const float* __restrict__ W2, const float* __restrict__ b2,
                         float* __restrict__ ws, float* __restrict__ out){
  int tid = threadIdx.x;
  int c = blockIdx.x*256 + tid;
  __shared__ float o1[BB*HH];   // 16 KB
  __shared__ float lmax[4*BB];
  for(int i=tid;i<BB*HH;i+=256) o1[i] = ws[OFF_OUT1 + i];
  __syncthreads();
  bool ok = c < VV;
  float acc[BB] = {};
  if(ok){
    for(int k=0;k<HH;k++){
      float wv = W2[(size_t)k*VV + c];
      #pragma unroll
      for(int bb=0;bb<BB;bb++) acc[bb] += o1[bb*HH+k]*wv;
    }
  }
  float bias = ok ? b2[c] : 0.0f;
  int lane = tid & 63, w = tid >> 6;
  #pragma unroll
  for(int bb=0;bb<BB;bb++){
    float v = ok ? (acc[bb]+bias) : -1e30f;
    if(ok) out[(size_t)bb*VOO + c] = v;
    float mv = wave_max(v);
    if(lane==0) lmax[w*BB+bb] = mv;
  }
  __syncthreads();
  if(tid < BB){
    float m = fmaxf(fmaxf(lmax[tid],lmax[BB+tid]), fmaxf(lmax[2*BB+tid],lmax[3*BB+tid]));
    ws[OFF_PMAX + blockIdx.x*BB + tid] = m;
  }
}

// exp(logit - max) in place + per-block per-b sums.  grid 196 x 256
__global__ void k_vexp(float* __restrict__ ws, float* __restrict__ out){
  int tid = threadIdx.x;
  int c = blockIdx.x*256 + tid;
  __shared__ float vmax[BB];
  __shared__ float lsum[4*BB];
  if(tid < BB){
    float m = -1e30f;
    for(int i=0;i<NVBLK;i++) m = fmaxf(m, ws[OFF_PMAX + i*BB + tid]);
    vmax[tid] = m;
  }
  __syncthreads();
  bool ok = c < VV;
  int lane = tid & 63, w = tid >> 6;
  #pragma unroll
  for(int bb=0;bb<BB;bb++){
    float e = 0.0f;
    if(ok){
      e = expf(out[(size_t)bb*VOO + c] - vmax[bb]);
      out[(size_t)bb*VOO + c] = e;
    }
    float sv = wave_sum(e);
    if(lane==0) lsum[w*BB+bb] = sv;
  }
  __syncthreads();
  if(tid < BB){
    ws[OFF_PSUM + blockIdx.x*BB + tid] =
      lsum[tid] + lsum[BB+tid] + lsum[2*BB+tid] + lsum[3*BB+tid];
  }
}

// final_dist = p_gen * e / sum  (v < V), extra_zeros tail.  grid (196,16) x 256
__global__ void k_final(const float* __restrict__ xz, float* __restrict__ ws,
                        float* __restrict__ out){
  int b = blockIdx.y;
  int v = blockIdx.x*256 + threadIdx.x;
  __shared__ float red[4];
  int lane = threadIdx.x & 63, w = threadIdx.x >> 6;
  float p = 0.0f;
  for(int i=threadIdx.x;i<NVBLK;i+=256) p += ws[OFF_PSUM + i*BB + b];
  p = wave_sum(p);
  if(lane==0) red[w] = p;
  __syncthreads();
  float s = red[0]+red[1]+red[2]+red[3];
  float pg = ws[OFF_PGEN + b];
  if(v < VV)       out[(size_t)b*VOO + v] = pg * out[(size_t)b*VOO + v] / s;
  else if(v < VOO) out[(size_t)b*VOO + v] = xz[b*OOVV + (v-VV)];
}

// scatter-add (1-p_gen)*attn at extend-vocab indices.  grid 16 x 256
__global__ void k_scatter(const int* __restrict__ ebev, float* __restrict__ ws,
                          float* __restrict__ out){
  int b = blockIdx.x;
  float r = 1.0f - ws[OFF_PGEN + b];
  for(int j=threadIdx.x;j<STK;j+=256){
    int idx = ebev[b*STK + j];
    atomicAdd(&out[(size_t)b*VOO + idx], r*out[O_ATTN + b*STK + j]);
  }
}

extern "C" void kernel_launch(void* const* d_in, const int* in_sizes, int n_in,
                              void* d_out, int out_size, void* d_ws, size_t ws_size,
                              hipStream_t stream){
  const int*   y     = (const int*)  d_in[0];
  const float* h0    = (const float*)d_in[1];
  const float* c0    = (const float*)d_in[2];
  const float* enc   = (const float*)d_in[3];
  const float* sec   = (const float*)d_in[4];
  const float* mask  = (const float*)d_in[5];
  const float* ct1   = (const float*)d_in[6];
  const float* xz    = (const float*)d_in[7];
  const int*   ebev  = (const int*)  d_in[8];
  const float* cover = (const float*)d_in[9];
  /* d_in[10] = gamma (unused by reference) */
  const float* emb   = (const float*)d_in[11];
  const float* Wxc   = (const float*)d_in[12];
  const float* bxc   = (const float*)d_in[13];
  const float* Wih   = (const float*)d_in[14];
  const float* bih   = (const float*)d_in[15];
  const float* Whh   = (const float*)d_in[16];
  const float* bhh   = (const float*)d_in[17];
  const float* Whsec = (const float*)d_in[18];
  const float* Wdsec = (const float*)d_in[19];
  const float* bdsec = (const float*)d_in[20];
  const float* vsec  = (const float*)d_in[21];
  const float* Whw   = (const float*)d_in[22];
  const float* Wcw   = (const float*)d_in[23];
  const float* Wdw   = (const float*)d_in[24];
  const float* bdw   = (const float*)d_in[25];
  const float* vw    = (const float*)d_in[26];
  const float* Wp    = (const float*)d_in[27];
  const float* bp    = (const float*)d_in[28];
  const float* Wo1   = (const float*)d_in[29];
  const float* bo1   = (const float*)d_in[30];
  const float* Wo2   = (const float*)d_in[31];
  const float* bo2   = (const float*)d_in[32];
  float* out = (float*)d_out;
  float* ws  = (float*)d_ws;

  k_zero   <<<dim3(232),      dim3(256), 0, stream>>>(ws);
  k_x      <<<dim3(BB),       dim3(128), 0, stream>>>(y, ct1, emb, Wxc, bxc, ws);
  k_lstm   <<<dim3(BB),       dim3(256), 0, stream>>>(h0, c0, Wih, bih, Whh, bhh, ws, out);
  k_proj   <<<dim3(BB,4),     dim3(256), 0, stream>>>(Wdsec, bdsec, Wdw, bdw, ws);
  k_esec   <<<dim3(BB,SS),    dim3(256), 0, stream>>>(sec, Whsec, vsec, ws);
  k_beta   <<<dim3(1),        dim3(64),  0, stream>>>(ws);
  k_gemm   <<<dim3(800,8),    dim3(256), 0, stream>>>(enc, Whw, Wcw, vw, cover, ws);
  k_attn   <<<dim3(BB),       dim3(256), 0, stream>>>(mask, cover, ws, out);
  k_ct     <<<dim3(25,BB),    dim3(256), 0, stream>>>(enc, out, ws);
  k_pgen   <<<dim3(BB),       dim3(256), 0, stream>>>(Wp, bp, Wo1, bo1, ws, out);
  k_logits <<<dim3(NVBLK),    dim3(256), 0, stream>>>(Wo2, bo2, ws, out);
  k_vexp   <<<dim3(NVBLK),    dim3(256), 0, stream>>>(ws, out);
  k_final  <<<dim3(NVBLK,BB), dim3(256), 0, stream>>>(xz, ws, out);
  k_scatter<<<dim3(BB),       dim3(256), 0, stream>>>(ebev, ws, out);
}

// Round 2
// 716.185 us; speedup vs baseline: 1.2607x; 1.2607x over previous
//
#include <hip/hip_runtime.h>
#include <math.h>

// ---- problem dims ----
#define BB   16
#define SS   8
#define TKK  400
#define HH   256
#define EE   128
#define VV   50000
#define OOVV 50
#define HH2  512
#define STK  (SS*TKK)     // 3200
#define VOO  (VV+OOVV)    // 50050
#define NVBLK 196         // ceil(50000/256)

// ---- workspace offsets (floats) ----
#define OFF_X     0        // B*E      = 2048
#define OFF_ST    2048     // B*H2     = 8192   s_t_hat = [h,c]
#define OFF_SD    10240    // B*H2     = 8192   s_t_hat@Wd_sec+bd_sec
#define OFF_WD    18432    // B*H2     = 8192   s_t_hat@Wd_w+bd_w
#define OFF_BETA  26624    // B*S      = 128
#define OFF_SCSEC 26752    // B*S      = 128
#define OFF_SCW   26880    // B*S*TK   = 51200  (plain stores from k_gemm2)
#define OFF_CT    78080    // B*H2     = 8192   (zero-init, atomic accum)
#define OFF_OUT1  86272    // B*H      = 4096
#define OFF_PGEN  90368    // B        = 16
#define OFF_PMAX  90384    // NVBLK*B  = 3136
#define OFF_PSUM  93520    // NVBLK*B  = 3136
#define OFF_BT    96768    // 512*512 bf16 = 131072 floats worth of ushort (512KB)

// ---- output offsets (floats) ----
#define O_FD   0
#define O_H    800800
#define O_C    804896
#define O_CT   808992
#define O_ATTN 817184
#define O_PGEN 868384
#define O_COV  868400

typedef __attribute__((ext_vector_type(8))) short bf16x8;
typedef __attribute__((ext_vector_type(4))) float f32x4;

__device__ __forceinline__ float sigm(float x){ return 1.0f/(1.0f+expf(-x)); }

__device__ __forceinline__ unsigned short f2b(float f){
  unsigned int u = __float_as_uint(f);
  unsigned int r = (u + 0x7fffu + ((u >> 16) & 1u)) >> 16;
  return (unsigned short)r;
}

__device__ __forceinline__ float wave_sum(float v){
  #pragma unroll
  for(int o=32;o>0;o>>=1) v += __shfl_xor(v,o);
  return v;
}
__device__ __forceinline__ float wave_max(float v){
  #pragma unroll
  for(int o=32;o>0;o>>=1) v = fmaxf(v,__shfl_xor(v,o));
  return v;
}

// zero CT (8192 floats). grid 32x256
__global__ void k_zero(float* ws){
  int i = blockIdx.x*256 + threadIdx.x;
  ws[OFF_CT + i] = 0.0f;
}

// transpose Whw [512k][512n] fp32 -> Bt [512n][512k] bf16.  grid (8,8) x 256
__global__ void k_bt(const float* __restrict__ Whw, unsigned short* __restrict__ Bt){
  __shared__ float tile[64][65];
  int n0 = blockIdx.x*64, k0 = blockIdx.y*64;
  int tx = threadIdx.x & 63, ty = threadIdx.x >> 6;  // ty 0..3
  #pragma unroll
  for(int it=0; it<16; it++){
    int kk = it*4 + ty;
    tile[kk][tx] = Whw[(size_t)(k0+kk)*HH2 + n0 + tx];
  }
  __syncthreads();
  #pragma unroll
  for(int it=0; it<16; it++){
    int nn = it*4 + ty;
    Bt[(size_t)(n0+nn)*HH2 + k0 + tx] = f2b(tile[tx][nn]);
  }
}

// x = [c_t_1, emb[y]] @ W_xc + b_xc   grid 16 x 128
__global__ void k_x(const int* __restrict__ y, const float* __restrict__ ct1,
                    const float* __restrict__ emb, const float* __restrict__ Wxc,
                    const float* __restrict__ bxc, float* __restrict__ ws){
  int b = blockIdx.x, e = threadIdx.x;
  __shared__ float cat[HH2+EE];
  for(int k=e;k<HH2;k+=EE) cat[k] = ct1[b*HH2+k];
  int tok = y[b];
  cat[HH2+e] = emb[(size_t)tok*EE + e];
  __syncthreads();
  float acc = bxc[e];
  for(int k=0;k<HH2+EE;k++) acc += cat[k]*Wxc[k*EE+e];
  ws[OFF_X + b*EE + e] = acc;
}

// LSTM step -> h, c, s_t_hat.  grid 16 x 256
__global__ void k_lstm(const float* __restrict__ h0, const float* __restrict__ c0,
                       const float* __restrict__ Wih, const float* __restrict__ bih,
                       const float* __restrict__ Whh, const float* __restrict__ bhh,
                       float* __restrict__ ws, float* __restrict__ out){
  int b = blockIdx.x, j = threadIdx.x;
  __shared__ float xr[EE], hr[HH];
  if(j<EE) xr[j] = ws[OFF_X + b*EE + j];
  hr[j] = h0[b*HH+j];
  __syncthreads();
  float a0 = bih[j      ] + bhh[j      ];
  float a1 = bih[j+HH   ] + bhh[j+HH   ];
  float a2 = bih[j+2*HH ] + bhh[j+2*HH ];
  float a3 = bih[j+3*HH ] + bhh[j+3*HH ];
  for(int k=0;k<EE;k++){
    float a = xr[k]; const float* w = &Wih[k*4*HH + j];
    a0 += a*w[0]; a1 += a*w[HH]; a2 += a*w[2*HH]; a3 += a*w[3*HH];
  }
  for(int k=0;k<HH;k++){
    float a = hr[k]; const float* w = &Whh[k*4*HH + j];
    a0 += a*w[0]; a1 += a*w[HH]; a2 += a*w[2*HH]; a3 += a*w[3*HH];
  }
  float ig = sigm(a0), fg = sigm(a1), gg = tanhf(a2), og = sigm(a3);
  float c = fg*c0[b*HH+j] + ig*gg;
  float h = og*tanhf(c);
  out[O_H + b*HH + j] = h;
  out[O_C + b*HH + j] = c;
  ws[OFF_ST + b*HH2 + j]      = h;
  ws[OFF_ST + b*HH2 + HH + j] = c;
}

// sd = st@Wd_sec+bd_sec ; wd = st@Wd_w+bd_w.  grid (16,4) x 256
__global__ void k_proj(const float* __restrict__ Wdsec, const float* __restrict__ bdsec,
                       const float* __restrict__ Wdw,  const float* __restrict__ bdw,
                       float* __restrict__ ws){
  int b = blockIdx.x;
  int idx = blockIdx.y*256 + threadIdx.x;   // 0..1023
  __shared__ float st[HH2];
  st[threadIdx.x]     = ws[OFF_ST + b*HH2 + threadIdx.x];
  st[256+threadIdx.x] = ws[OFF_ST + b*HH2 + 256 + threadIdx.x];
  __syncthreads();
  const float* Wm; const float* bias; int n; float* dst;
  if(idx < HH2){ n = idx;       Wm = Wdsec; bias = bdsec; dst = &ws[OFF_SD + b*HH2 + n]; }
  else         { n = idx - HH2; Wm = Wdw;   bias = bdw;   dst = &ws[OFF_WD + b*HH2 + n]; }
  float acc = bias[n];
  for(int k=0;k<HH2;k++) acc += st[k]*Wm[k*HH2 + n];
  *dst = acc;
}

// section attention scores.  grid (16,8) x 256
__global__ void k_esec(const float* __restrict__ sec, const float* __restrict__ Whsec,
                       const float* __restrict__ vsec, float* __restrict__ ws){
  int b = blockIdx.x, s = blockIdx.y, tid = threadIdx.x;
  __shared__ float row[HH2];
  __shared__ float red[4];
  row[tid]     = sec[(b*SS+s)*HH2 + tid];
  row[256+tid] = sec[(b*SS+s)*HH2 + 256 + tid];
  __syncthreads();
  float part = 0.0f;
  #pragma unroll
  for(int rep=0;rep<2;rep++){
    int n = rep*256 + tid;
    float acc = ws[OFF_SD + b*HH2 + n];
    for(int k=0;k<HH2;k++) acc += row[k]*Whsec[k*HH2 + n];
    part += tanhf(acc)*vsec[n];
  }
  part = wave_sum(part);
  if((tid&63)==0) red[tid>>6] = part;
  __syncthreads();
  if(tid==0) ws[OFF_SCSEC + b*SS + s] = red[0]+red[1]+red[2]+red[3];
}

// beta = softmax(sc_sec)/sum.  1 block x 64
__global__ void k_beta(float* __restrict__ ws){
  int b = threadIdx.x;
  if(b < BB){
    float m = -1e30f;
    for(int s=0;s<SS;s++) m = fmaxf(m, ws[OFF_SCSEC+b*SS+s]);
    float e[SS]; float sum=0.0f;
    for(int s=0;s<SS;s++){ e[s] = expf(ws[OFF_SCSEC+b*SS+s]-m); sum += e[s]; }
    float sum2 = 0.0f;
    for(int s=0;s<SS;s++) sum2 += e[s]/sum;
    for(int s=0;s<SS;s++) ws[OFF_BETA+b*SS+s] = (e[s]/sum)/sum2;
  }
}

// MFMA fused GEMM: for 128 rows, all 512 cols (4 col-chunks), K=512.
// sc_w[row] = sum_n tanh(enc[row,:]@Whw[:,n] + wd[b,n] + cov[row]*Wcw[n]) * vw[n]
// grid 400 x 256.  Wave w owns rows w*32..w*32+31 across all cols -> plain store.
__global__ __launch_bounds__(256) void k_gemm2(
        const float* __restrict__ A, const unsigned short* __restrict__ Bt,
        const float* __restrict__ Wcw, const float* __restrict__ vw,
        const float* __restrict__ cover, float* __restrict__ ws){
  __shared__ __align__(16) unsigned short As[128*72];  // [row][k], pad 64->72
  __shared__ __align__(16) unsigned short Bs[128*72];  // [col][k], pad 64->72
  int tid = threadIdx.x;
  int w = tid >> 6, lane = tid & 63;
  int m = lane & 15, q = lane >> 4;
  int row0 = blockIdx.x * 128;
  int b = row0 / STK;             // 3200 % 128 == 0, tile never crosses batch
  int wrow = w * 32;
  float cov[2][4];
  #pragma unroll
  for(int i=0;i<2;i++)
    #pragma unroll
    for(int r=0;r<4;r++) cov[i][r] = cover[row0 + wrow + i*16 + q*4 + r];
  float rsum[2][4] = {};
  for(int cb=0; cb<4; cb++){
    int col0 = cb*128;
    f32x4 acc[2][8];
    #pragma unroll
    for(int i=0;i<2;i++)
      #pragma unroll
      for(int j=0;j<8;j++) acc[i][j] = (f32x4){0.f,0.f,0.f,0.f};
    for(int k0=0; k0<HH2; k0+=64){
      // stage A (fp32->bf16) and B (bf16) tiles
      #pragma unroll
      for(int qq=0; qq<4; qq++){
        int c = tid + 256*qq;           // 0..1023
        int r = c >> 3, kc = (c & 7) * 8;
        const float4* pa = (const float4*)&A[(size_t)(row0 + r)*HH2 + k0 + kc];
        float4 v0 = pa[0], v1 = pa[1];
        union { bf16x8 v; unsigned short u[8]; } t;
        t.u[0]=f2b(v0.x); t.u[1]=f2b(v0.y); t.u[2]=f2b(v0.z); t.u[3]=f2b(v0.w);
        t.u[4]=f2b(v1.x); t.u[5]=f2b(v1.y); t.u[6]=f2b(v1.z); t.u[7]=f2b(v1.w);
        *(bf16x8*)&As[r*72 + kc] = t.v;
        bf16x8 bv = *(const bf16x8*)&Bt[(size_t)(col0 + r)*HH2 + k0 + kc];
        *(bf16x8*)&Bs[r*72 + kc] = bv;
      }
      __syncthreads();
      #pragma unroll
      for(int kk=0; kk<64; kk+=32){
        bf16x8 af[2], bfr[8];
        #pragma unroll
        for(int i=0;i<2;i++) af[i] = *(bf16x8*)&As[(wrow + i*16 + m)*72 + kk + q*8];
        #pragma unroll
        for(int j=0;j<8;j++) bfr[j] = *(bf16x8*)&Bs[(j*16 + m)*72 + kk + q*8];
        #pragma unroll
        for(int i=0;i<2;i++)
          #pragma unroll
          for(int j=0;j<8;j++)
            acc[i][j] = __builtin_amdgcn_mfma_f32_16x16x32_bf16(af[i], bfr[j], acc[i][j], 0,0,0);
      }
      __syncthreads();
    }
    // epilogue: fold this col-chunk into per-row sums
    #pragma unroll
    for(int j=0;j<8;j++){
      int col = col0 + j*16 + m;
      float wdv = ws[OFF_WD + b*HH2 + col];
      float wcv = Wcw[col], vwv = vw[col];
      #pragma unroll
      for(int i=0;i<2;i++)
        #pragma unroll
        for(int r=0;r<4;r++)
          rsum[i][r] += tanhf(acc[i][j][r] + wdv + cov[i][r]*wcv) * vwv;
    }
  }
  #pragma unroll
  for(int i=0;i<2;i++)
    #pragma unroll
    for(int r=0;r<4;r++){
      float v = rsum[i][r];
      v += __shfl_xor(v, 1, 16); v += __shfl_xor(v, 2, 16);
      v += __shfl_xor(v, 4, 16); v += __shfl_xor(v, 8, 16);
      if(m == 0) ws[OFF_SCW + row0 + wrow + i*16 + q*4 + r] = v;
    }
}

// attn softmax over 3200 with beta weighting + mask + renorm; also coverage out.
// grid 16 x 256
__global__ void k_attn(const float* __restrict__ mask, const float* __restrict__ cover,
                       float* __restrict__ ws, float* __restrict__ out){
  int b = blockIdx.x, tid = threadIdx.x;
  __shared__ float vals[STK];
  __shared__ float red[4];
  int lane = tid & 63, w = tid >> 6;
  float m = -1e30f;
  for(int j=tid;j<STK;j+=256){
    float v = ws[OFF_BETA + b*SS + j/TKK] * ws[OFF_SCW + b*STK + j];
    vals[j] = v; m = fmaxf(m, v);
  }
  m = wave_max(m);
  if(lane==0) red[w] = m;
  __syncthreads();
  m = fmaxf(fmaxf(red[0],red[1]), fmaxf(red[2],red[3]));
  __syncthreads();
  float ssum = 0.0f;
  for(int j=tid;j<STK;j+=256){
    float e = expf(vals[j]-m) * mask[b*STK + j];
    vals[j] = e; ssum += e;
  }
  ssum = wave_sum(ssum);
  if(lane==0) red[w] = ssum;
  __syncthreads();
  float inv = 1.0f/(red[0]+red[1]+red[2]+red[3]);
  for(int j=tid;j<STK;j+=256){
    float a = vals[j]*inv;
    out[O_ATTN + b*STK + j] = a;
    out[O_COV  + b*STK + j] = cover[b*STK + j] + a;
  }
}

// c_t = attn @ enc.  grid (25,16) x 256, atomic accumulate
__global__ void k_ct(const float* __restrict__ enc, const float* __restrict__ out,
                     float* __restrict__ ws){
  int b = blockIdx.y, tc = blockIdx.x, tid = threadIdx.x;
  __shared__ float a[128];
  int t0 = tc*128;
  if(tid<128) a[tid] = out[O_ATTN + b*STK + t0 + tid];
  __syncthreads();
  float acc0=0.0f, acc1=0.0f;
  for(int tt=0;tt<128;tt++){
    const float* row = &enc[(size_t)(b*STK + t0 + tt)*HH2];
    float av = a[tt];
    acc0 += av*row[tid];
    acc1 += av*row[256+tid];
  }
  atomicAdd(&ws[OFF_CT + b*HH2 + tid],       acc0);
  atomicAdd(&ws[OFF_CT + b*HH2 + 256 + tid], acc1);
}

// p_gen + out1 + copy c_t to output.  grid 16 x 256
__global__ void k_pgen(const float* __restrict__ Wp, const float* __restrict__ bp,
                       const float* __restrict__ Wo1, const float* __restrict__ bo1,
                       float* __restrict__ ws, float* __restrict__ out){
  int b = blockIdx.x, tid = threadIdx.x;
  __shared__ float cat[4*HH+EE];  // [c_t(512), st(512), x(128)]
  __shared__ float red[4];
  cat[tid]       = ws[OFF_CT + b*HH2 + tid];
  cat[256+tid]   = ws[OFF_CT + b*HH2 + 256 + tid];
  cat[512+tid]   = ws[OFF_ST + b*HH2 + tid];
  cat[768+tid]   = ws[OFF_ST + b*HH2 + 256 + tid];
  if(tid<EE) cat[1024+tid] = ws[OFF_X + b*EE + tid];
  __syncthreads();
  float p = 0.0f;
  for(int k=tid;k<4*HH+EE;k+=256) p += cat[k]*Wp[k];
  p = wave_sum(p);
  if((tid&63)==0) red[tid>>6] = p;
  __syncthreads();
  if(tid==0){
    float pg = sigm(red[0]+red[1]+red[2]+red[3] + bp[0]);
    ws[OFF_PGEN + b] = pg;
    out[O_PGEN + b]  = pg;
  }
  float acc = bo1[tid];
  for(int k=0;k<HH;k++)  acc += cat[512+k]*Wo1[k*HH + tid];
  for(int k=0;k<HH2;k++) acc += cat[k]*Wo1[(HH+k)*HH + tid];
  ws[OFF_OUT1 + b*HH + tid] = acc;
  out[O_CT + b*HH2 + tid]       = cat[tid];
  out[O_CT + b*HH2 + 256 + tid] = cat[256+tid];
}

// logits -> final_dist area (in place), per-block per-b max.  grid 196 x 256
__global__ void k_logits(const float* __restrict__ W2, const float* __restrict__ b2,
                         float* __restrict__ ws, float* __restrict__ out){
  int tid = threadIdx.x;
  int c = blockIdx.x*256 + tid;
  __shared__ float o1[BB*HH];   // 16 KB
  __shared__ float lmax[4*BB];
  for(int i=tid;i<BB*HH;i+=256) o1[i] = ws[OFF_OUT1 + i];
  __syncthreads();
  bool ok = c < VV;
  float acc[BB] = {};
  if(ok){
    for(int k=0;k<HH;k++){
      float wv = W2[(size_t)k*VV + c];
      #pragma unroll
      for(int bb=0;bb<BB;bb++) acc[bb] += o1[bb*HH+k]*wv;
    }
  }
  float bias = ok ? b2[c] : 0.0f;
  int lane = tid & 63, w = tid >> 6;
  #pragma unroll
  for(int bb=0;bb<BB;bb++){
    float v = ok ? (acc[bb]+bias) : -1e30f;
    if(ok) out[(size_t)bb*VOO + c] = v;
    float mv = wave_max(v);
    if(lane==0) lmax[w*BB+bb] = mv;
  }
  __syncthreads();
  if(tid < BB){
    float m = fmaxf(fmaxf(lmax[tid],lmax[BB+tid]), fmaxf(lmax[2*BB+tid],lmax[3*BB+tid]));
    ws[OFF_PMAX + blockIdx.x*BB + tid] = m;
  }
}

// exp(logit - max) in place + per-block per-b sums.  grid 196 x 256
__global__ void k_vexp(float* __restrict__ ws, float* __restrict__ out){
  int tid = threadIdx.x;
  int c = blockIdx.x*256 + tid;
  __shared__ float vmax[BB];
  __shared__ float lsum[4*BB];
  if(tid < BB){
    float m = -1e30f;
    for(int i=0;i<NVBLK;i++) m = fmaxf(m, ws[OFF_PMAX + i*BB + tid]);
    vmax[tid] = m;
  }
  __syncthreads();
  bool ok = c < VV;
  int lane = tid & 63, w = tid >> 6;
  #pragma unroll
  for(int bb=0;bb<BB;bb++){
    float e = 0.0f;
    if(ok){
      e = expf(out[(size_t)bb*VOO + c] - vmax[bb]);
      out[(size_t)bb*VOO + c] = e;
    }
    float sv = wave_sum(e);
    if(lane==0) lsum[w*BB+bb] = sv;
  }
  __syncthreads();
  if(tid < BB){
    ws[OFF_PSUM + blockIdx.x*BB + tid] =
      lsum[tid] + lsum[BB+tid] + lsum[2*BB+tid] + lsum[3*BB+tid];
  }
}

// final_dist = p_gen * e / sum  (v < V), extra_zeros tail.  grid (196,16) x 256
__global__ void k_final(const float* __restrict__ xz, float* __restrict__ ws,
                        float* __restrict__ out){
  int b = blockIdx.y;
  int v = blockIdx.x*256 + threadIdx.x;
  __shared__ float red[4];
  int lane = threadIdx.x & 63, w = threadIdx.x >> 6;
  float p = 0.0f;
  for(int i=threadIdx.x;i<NVBLK;i+=256) p += ws[OFF_PSUM + i*BB + b];
  p = wave_sum(p);
  if(lane==0) red[w] = p;
  __syncthreads();
  float s = red[0]+red[1]+red[2]+red[3];
  float pg = ws[OFF_PGEN + b];
  if(v < VV)       out[(size_t)b*VOO + v] = pg * out[(size_t)b*VOO + v] / s;
  else if(v < VOO) out[(size_t)b*VOO + v] = xz[b*OOVV + (v-VV)];
}

// scatter-add (1-p_gen)*attn at extend-vocab indices.  grid 16 x 256
__global__ void k_scatter(const int* __restrict__ ebev, float* __restrict__ ws,
                          float* __restrict__ out){
  int b = blockIdx.x;
  float r = 1.0f - ws[OFF_PGEN + b];
  for(int j=threadIdx.x;j<STK;j+=256){
    int idx = ebev[b*STK + j];
    atomicAdd(&out[(size_t)b*VOO + idx], r*out[O_ATTN + b*STK + j]);
  }
}

extern "C" void kernel_launch(void* const* d_in, const int* in_sizes, int n_in,
                              void* d_out, int out_size, void* d_ws, size_t ws_size,
                              hipStream_t stream){
  const int*   y     = (const int*)  d_in[0];
  const float* h0    = (const float*)d_in[1];
  const float* c0    = (const float*)d_in[2];
  const float* enc   = (const float*)d_in[3];
  const float* sec   = (const float*)d_in[4];
  const float* mask  = (const float*)d_in[5];
  const float* ct1   = (const float*)d_in[6];
  const float* xz    = (const float*)d_in[7];
  const int*   ebev  = (const int*)  d_in[8];
  const float* cover = (const float*)d_in[9];
  /* d_in[10] = gamma (unused by reference) */
  const float* emb   = (const float*)d_in[11];
  const float* Wxc   = (const float*)d_in[12];
  const float* bxc   = (const float*)d_in[13];
  const float* Wih   = (const float*)d_in[14];
  const float* bih   = (const float*)d_in[15];
  const float* Whh   = (const float*)d_in[16];
  const float* bhh   = (const float*)d_in[17];
  const float* Whsec = (const float*)d_in[18];
  const float* Wdsec = (const float*)d_in[19];
  const float* bdsec = (const float*)d_in[20];
  const float* vsec  = (const float*)d_in[21];
  const float* Whw   = (const float*)d_in[22];
  const float* Wcw   = (const float*)d_in[23];
  const float* Wdw   = (const float*)d_in[24];
  const float* bdw   = (const float*)d_in[25];
  const float* vw    = (const float*)d_in[26];
  const float* Wp    = (const float*)d_in[27];
  const float* bp    = (const float*)d_in[28];
  const float* Wo1   = (const float*)d_in[29];
  const float* bo1   = (const float*)d_in[30];
  const float* Wo2   = (const float*)d_in[31];
  const float* bo2   = (const float*)d_in[32];
  float* out = (float*)d_out;
  float* ws  = (float*)d_ws;
  unsigned short* Bt = (unsigned short*)(ws + OFF_BT);

  k_zero   <<<dim3(32),       dim3(256), 0, stream>>>(ws);
  k_bt     <<<dim3(8,8),      dim3(256), 0, stream>>>(Whw, Bt);
  k_x      <<<dim3(BB),       dim3(128), 0, stream>>>(y, ct1, emb, Wxc, bxc, ws);
  k_lstm   <<<dim3(BB),       dim3(256), 0, stream>>>(h0, c0, Wih, bih, Whh, bhh, ws, out);
  k_proj   <<<dim3(BB,4),     dim3(256), 0, stream>>>(Wdsec, bdsec, Wdw, bdw, ws);
  k_esec   <<<dim3(BB,SS),    dim3(256), 0, stream>>>(sec, Whsec, vsec, ws);
  k_beta   <<<dim3(1),        dim3(64),  0, stream>>>(ws);
  k_gemm2  <<<dim3(400),      dim3(256), 0, stream>>>(enc, Bt, Wcw, vw, cover, ws);
  k_attn   <<<dim3(BB),       dim3(256), 0, stream>>>(mask, cover, ws, out);
  k_ct     <<<dim3(25,BB),    dim3(256), 0, stream>>>(enc, out, ws);
  k_pgen   <<<dim3(BB),       dim3(256), 0, stream>>>(Wp, bp, Wo1, bo1, ws, out);
  k_logits <<<dim3(NVBLK),    dim3(256), 0, stream>>>(Wo2, bo2, ws, out);
  k_vexp   <<<dim3(NVBLK),    dim3(256), 0, stream>>>(ws, out);
  k_final  <<<dim3(NVBLK,BB), dim3(256), 0, stream>>>(xz, ws, out);
  k_scatter<<<dim3(BB),       dim3(256), 0, stream>>>(ebev, ws, out);
}